// Round 2
// baseline (450.014 us; speedup 1.0000x reference)
//
#include <hip/hip_runtime.h>

// Problem constants (setup_inputs fixed):
//   x:         (B=16, L=512, D=768) fp32   = 25.2 MB  (L2/L3-resident)
//   width_emb: (W=8, WD=64) fp32           = 2 KB
//   out: (B=16, n_spans=4068, 1600) fp32   = 416.56 MB (write-once stream)
typedef float f32x4 __attribute__((ext_vector_type(4)));

constexpr uint32_t B      = 16;
constexpr uint32_t L      = 512;
constexpr uint32_t D4     = 768 / 4;    // 192 f4 per x row
constexpr uint32_t WD4    = 64 / 4;     // 16 f4 per width_emb row
constexpr uint32_t NSPANS = 4068;
constexpr uint32_t ROW_F4 = 2 * D4 + WD4;            // 400 f4 per out row
constexpr uint32_t TOTAL_F4 = B * NSPANS * ROW_F4;   // 26,035,200

constexpr uint32_t TPB  = 256;
constexpr uint32_t NBLK = 2825;                      // chosen so:
constexpr uint32_t T    = TPB * NBLK;                // 723,200 = 400*1808  (400 | T → c loop-invariant)
constexpr uint32_t NITER = TOTAL_F4 / T;             // 36 EXACT (no tail, no bounds checks)
static_assert(NITER * T == TOTAL_F4, "exact cover");
static_assert(T % ROW_F4 == 0, "c invariant");
constexpr uint32_t DS = T / ROW_F4;                  // 1808 rows advanced per iter (< NSPANS)
constexpr uint32_t XB_STRIDE = L * D4;               // 98,304 f4 per batch of x
constexpr uint32_t U = 4;                            // loads in flight per wave; 36 = 9*4

__global__ __launch_bounds__(TPB) void span_rep_kernel(
    const f32x4* __restrict__ x4,
    const f32x4* __restrict__ w4,
    f32x4* __restrict__ out4) {
  uint32_t idx = blockIdx.x * TPB + threadIdx.x;     // < T

  // One-time setup (magic-mul divisions, per thread).
  const uint32_t c = idx % ROW_F4;                   // loop-invariant column
  uint32_t r = idx / ROW_F4;                         // r < 1808 => b=0, s=r initially
  uint32_t s  = r;                                   // span index within batch
  uint32_t xb = 0;                                   // b * XB_STRIDE, maintained incrementally

  // Per-thread-constant segment decode (no branches in the hot loop).
  const bool     isW   = c >= 2 * D4;                // width-emb segment
  const bool     isMid = (c >= D4) && !isW;          // h_end segment
  const uint32_t c2    = isW ? 0u : (isMid ? c - D4 : c);
  const uint32_t cw    = isW ? c - 2 * D4 : 0u;

  for (uint32_t it = 0; it < NITER / U; ++it) {
    const f32x4* pv[U];
    uint32_t so[U];

    // Phase 1: compute U independent addresses (branch-free VALU only).
#pragma unroll
    for (uint32_t u = 0; u < U; ++u) {
      // Width bucket: first span index of bucket k is o(k)=512k - k(k-1)/2.
      uint32_t wid = 0;
#pragma unroll
      for (uint32_t k = 1; k < 8; ++k) {
        const uint32_t o = L * k - (k * (k - 1)) / 2;   // 512,1023,1533,2042,2550,3057,3563
        wid += (s >= o) ? 1u : 0u;
      }
      const uint32_t off   = (wid * (2u * L + 1u - wid)) >> 1;  // wid*(1025-wid)/2
      const uint32_t start = s - off;
      const uint32_t row   = start + (isMid ? wid : 0u);        // h_end adds wid

      const f32x4* px = x4 + (xb + row * D4 + c2);
      const f32x4* pw = w4 + (wid * WD4 + cw);
      pv[u] = isW ? pw : px;                                    // cndmask on pointer
      so[u] = idx;

      // Advance (branch-free): at most one batch wrap per step since DS < NSPANS.
      idx += T;
      s   += DS;
      const bool wrap = s >= NSPANS;
      s  -= wrap ? NSPANS : 0u;
      xb += wrap ? XB_STRIDE : 0u;
    }

    // Phase 2: U loads in flight.
    f32x4 v[U];
#pragma unroll
    for (uint32_t u = 0; u < U; ++u) v[u] = *pv[u];

    // Phase 3: U streaming stores (write-once; keep L2 for x).
#pragma unroll
    for (uint32_t u = 0; u < U; ++u)
      __builtin_nontemporal_store(v[u], &out4[so[u]]);
  }
}

extern "C" void kernel_launch(void* const* d_in, const int* in_sizes, int n_in,
                              void* d_out, int out_size, void* d_ws, size_t ws_size,
                              hipStream_t stream) {
  const f32x4* x4 = (const f32x4*)d_in[0];
  const f32x4* w4 = (const f32x4*)d_in[1];
  f32x4* out4 = (f32x4*)d_out;
  span_rep_kernel<<<dim3(NBLK), dim3(TPB), 0, stream>>>(x4, w4, out4);
}

// Round 3
// 436.980 us; speedup vs baseline: 1.0298x; 1.0298x over previous
//
#include <hip/hip_runtime.h>

// Problem constants (setup_inputs fixed):
//   x:   (B=16, L=512, D=768) fp32 = 25.2 MB
//   w:   (8, 64) fp32 = 2 KB
//   out: (B=16, n_spans=4068, 1600) fp32 = 416.56 MB write-once stream
//
// Decomposition for READ locality: block = (batch b, start-range p0..p0+7).
// The block emits output rows for ALL 8 width buckets of those start
// positions, so every use (start + end, all widths) of x rows
// p0..p0+14 happens within one block: ~45 KB working set, L2-resident,
// each x line fetched ~once per block (~46 MB total vs 400 MB logical).
// Writes remain contiguous 25.6 KB chunks per (block, bucket).
typedef float f32x4 __attribute__((ext_vector_type(4)));

constexpr uint32_t B      = 16;
constexpr uint32_t L      = 512;
constexpr uint32_t D4     = 768 / 4;            // 192 f4 per x row
constexpr uint32_t WD4    = 64 / 4;             // 16 f4 per w row
constexpr uint32_t NSPANS = 4068;
constexpr uint32_t ROW_F4 = 2 * D4 + WD4;       // 400 f4 per out row

constexpr uint32_t P    = 8;                    // start positions per block
constexpr uint32_t NPB  = L / P;                // 64 blocks per batch
constexpr uint32_t TPB  = 256;
constexpr uint32_t BUCKET_F4 = P * ROW_F4;      // 3200 f4 per (block,bucket)
constexpr uint32_t ITERS = (BUCKET_F4 + TPB - 1) / TPB;  // 13

__global__ __launch_bounds__(TPB) void span_rep_kernel(
    const f32x4* __restrict__ x4,
    const f32x4* __restrict__ w4,
    f32x4* __restrict__ out4) {
  const uint32_t bid = blockIdx.x;
  const uint32_t b   = bid >> 6;                 // bid / NPB
  const uint32_t p0  = (bid & 63u) * P;          // first start position
  const uint32_t t   = threadIdx.x;
  const uint32_t xb  = b * (L * D4);

  uint32_t ok = 0;                               // first span index of bucket k
  for (uint32_t k = 0; k < 8; ++k) {
    // Bucket k (width k+1) has L-k spans; this block owns starts
    // p0..p0+P-1, clipped at the bucket end (only the last block clips).
    const uint32_t nspan = min(P, L - k - p0);
    const uint32_t nval  = nspan * ROW_F4;
    const uint32_t obase = (b * NSPANS + ok + p0) * ROW_F4;

#pragma unroll
    for (uint32_t it = 0; it < ITERS; ++it) {
      const uint32_t e = it * TPB + t;           // f4 index within bucket chunk
      if (e < nval) {
        const uint32_t p   = e / ROW_F4;         // const divisor -> magic mul
        const uint32_t c   = e - p * ROW_F4;
        const uint32_t row = p0 + p;             // span start position
        f32x4 v;
        if (c < D4) {
          v = x4[xb + row * D4 + c];                       // h_start
        } else if (c < 2 * D4) {
          v = x4[xb + (row + k) * D4 + (c - D4)];          // h_end (end=start+k)
        } else {
          v = w4[k * WD4 + (c - 2 * D4)];                  // width emb
        }
        // write-once stream: keep caches for x
        __builtin_nontemporal_store(v, &out4[obase + e]);
      }
    }
    ok += L - k;
  }
}

extern "C" void kernel_launch(void* const* d_in, const int* in_sizes, int n_in,
                              void* d_out, int out_size, void* d_ws, size_t ws_size,
                              hipStream_t stream) {
  const f32x4* x4 = (const f32x4*)d_in[0];
  const f32x4* w4 = (const f32x4*)d_in[1];
  f32x4* out4 = (f32x4*)d_out;
  span_rep_kernel<<<dim3(B * NPB), dim3(TPB), 0, stream>>>(x4, w4, out4);
}

// Round 4
// 425.474 us; speedup vs baseline: 1.0577x; 1.0270x over previous
//
#include <hip/hip_runtime.h>

// x:   (B=16, L=512, D=768) fp32 = 25.2 MB
// w:   (8, 64) fp32 = 2 KB
// out: (16, 4068, 1600) fp32 = 416.56 MB write-once stream
//
// Round-4 structure: fully decouple global reads from the write stream.
// Block = (batch b, 8 consecutive start positions p0..p0+7). Stage the 15
// x rows the block can touch (h_start p0..p0+7, h_end up to p0+7+7) plus
// all of width_emb into LDS once (~48 KB, coalesced global loads). The
// hot loop is then pure ds_read_b128 -> nontemporal global_store: zero
// global loads coupled to stores, matching the structure of the 6.3 TB/s
// fill kernel as closely as a correct kernel can.
typedef float f32x4 __attribute__((ext_vector_type(4)));

constexpr uint32_t B      = 16;
constexpr uint32_t L      = 512;
constexpr uint32_t D4     = 768 / 4;            // 192 f4 per x row
constexpr uint32_t WD4    = 64 / 4;             // 16 f4 per w row
constexpr uint32_t NSPANS = 4068;
constexpr uint32_t ROW_F4 = 2 * D4 + WD4;       // 400 f4 per out row

constexpr uint32_t P     = 8;                   // start positions per block
constexpr uint32_t TPB   = 256;
constexpr uint32_t XROWS = P + 7;               // 15 x rows reachable
constexpr uint32_t XS_F4 = XROWS * D4;          // 2880 f4 = 46080 B
constexpr uint32_t WS_F4 = 8 * WD4;             // 128 f4 = 2048 B
constexpr uint32_t ITERS = (P * ROW_F4 + TPB - 1) / TPB;  // 13

__global__ __launch_bounds__(TPB) void span_rep_kernel(
    const f32x4* __restrict__ x4,
    const f32x4* __restrict__ w4,
    f32x4* __restrict__ out4) {
  __shared__ f32x4 xs[XS_F4];
  __shared__ f32x4 ws[WS_F4];

  const uint32_t bid = blockIdx.x;
  const uint32_t b   = bid >> 6;                 // bid / 64
  const uint32_t p0  = (bid & 63u) * P;
  const uint32_t t   = threadIdx.x;
  const uint32_t xb  = b * (L * D4);

  // ---- Stage: 15 x rows + width_emb into LDS (coalesced, once) ----
  for (uint32_t i = t; i < XS_F4; i += TPB) {
    const uint32_t row  = i / D4;                // const divisor -> magic mul
    const uint32_t c    = i - row * D4;
    const uint32_t grow = min(p0 + row, L - 1u); // clamp; clamped rows unused
    xs[i] = x4[xb + grow * D4 + c];
  }
  if (t < WS_F4) ws[t] = w4[t];
  __syncthreads();

  // ---- Emit: pure LDS-read -> streaming-store ----
  uint32_t ok = 0;                               // first span index of bucket k
  for (uint32_t k = 0; k < 8; ++k) {
    const uint32_t nspan = min(P, L - k - p0);   // clipped only at p0=504
    const uint32_t nval  = nspan * ROW_F4;
    const uint32_t obase = (b * NSPANS + ok + p0) * ROW_F4;

#pragma unroll
    for (uint32_t it = 0; it < ITERS; ++it) {
      const uint32_t e = it * TPB + t;
      if (e < nval) {
        const uint32_t p = e / ROW_F4;           // local span (0..7)
        const uint32_t c = e - p * ROW_F4;
        f32x4 v;
        if (c < D4) {
          v = xs[p * D4 + c];                    // h_start
        } else if (c < 2 * D4) {
          v = xs[(p + k) * D4 + (c - D4)];       // h_end (end = start + k)
        } else {
          v = ws[k * WD4 + (c - 2 * D4)];        // width emb
        }
        __builtin_nontemporal_store(v, &out4[obase + e]);
      }
    }
    ok += L - k;
  }
}

extern "C" void kernel_launch(void* const* d_in, const int* in_sizes, int n_in,
                              void* d_out, int out_size, void* d_ws, size_t ws_size,
                              hipStream_t stream) {
  const f32x4* x4 = (const f32x4*)d_in[0];
  const f32x4* w4 = (const f32x4*)d_in[1];
  f32x4* out4 = (f32x4*)d_out;
  span_rep_kernel<<<dim3(B * (L / P)), dim3(TPB), 0, stream>>>(x4, w4, out4);
}